// Round 1
// baseline (10979.858 us; speedup 1.0000x reference)
//
#include <hip/hip_runtime.h>
#include <math.h>

#define BSZ 2048
#define DIM 2048
#define MS 6
#define NIT 29          // k = 1..29
#define LAMREG 1e-4f
#define XROWS (MS*DIM)  // 12288: row stride of the (bsz, 6, d) layouts

// ---------------------------------------------------------------------------
// init: X[:,0] = x0 (into d_out X region), zero the 2*NIT norm accumulators
// ---------------------------------------------------------------------------
__global__ __launch_bounds__(256) void init_kernel(const float* __restrict__ x0,
                                                   float* __restrict__ Xout,
                                                   float* __restrict__ norms) {
    int idx = blockIdx.x * 256 + threadIdx.x;
    if (idx < 2 * NIT) norms[idx] = 0.0f;
    for (int i = idx; i < BSZ * DIM; i += gridDim.x * 256) {
        int b = i >> 11;
        int j = i & (DIM - 1);
        Xout[(size_t)b * XROWS + j] = x0[i];
    }
}

// ---------------------------------------------------------------------------
// fused GEMM + bias + tanh (+ optional ||f-x||^2, ||f||^2 accumulation)
// Out[r,c] = tanh( sum_k A[r,k]*W[k,c] + bias[c] ),  A row stride lda,
// Out row stride ldo. 128x128 tile, BK=16, 256 thr, 8x8 per thread.
// ---------------------------------------------------------------------------
#define BM 128
#define BN 128
#define BK 16

__global__ __launch_bounds__(256) void gemm_tanh_kernel(
    const float* __restrict__ A, int lda,
    const float* __restrict__ W,
    const float* __restrict__ bias,
    float* __restrict__ Out, int ldo,
    float* __restrict__ normAcc, int doNorm)
{
    __shared__ float As[BK][BM + 4];
    __shared__ float Bs[BK][BN + 4];
    const int tid = threadIdx.x;
    const int m0 = blockIdx.y * BM;
    const int n0 = blockIdx.x * BN;
    const int tx = tid & 15;   // n-dir
    const int ty = tid >> 4;   // m-dir

    // staging index split
    const int a_m = tid >> 2;         // 0..63
    const int a_k = (tid & 3) << 2;   // 0,4,8,12
    const int b_k = tid >> 5;         // 0..7
    const int b_n = (tid & 31) << 2;  // 0..124

    float acc[8][8];
#pragma unroll
    for (int i = 0; i < 8; i++)
#pragma unroll
        for (int j = 0; j < 8; j++) acc[i][j] = 0.0f;

    const float* Arow0 = A + (size_t)(m0 + a_m) * lda + a_k;
    const float* Arow1 = A + (size_t)(m0 + a_m + 64) * lda + a_k;
    const float* Wrow0 = W + (size_t)b_k * DIM + n0 + b_n;
    const float* Wrow1 = W + (size_t)(b_k + 8) * DIM + n0 + b_n;

    for (int k0 = 0; k0 < DIM; k0 += BK) {
        float4 av0 = *(const float4*)(Arow0 + k0);
        float4 av1 = *(const float4*)(Arow1 + k0);
        float4 bv0 = *(const float4*)(Wrow0 + (size_t)k0 * DIM);
        float4 bv1 = *(const float4*)(Wrow1 + (size_t)k0 * DIM);
        __syncthreads();
        As[a_k + 0][a_m] = av0.x;
        As[a_k + 1][a_m] = av0.y;
        As[a_k + 2][a_m] = av0.z;
        As[a_k + 3][a_m] = av0.w;
        As[a_k + 0][a_m + 64] = av1.x;
        As[a_k + 1][a_m + 64] = av1.y;
        As[a_k + 2][a_m + 64] = av1.z;
        As[a_k + 3][a_m + 64] = av1.w;
        *(float4*)&Bs[b_k][b_n] = bv0;
        *(float4*)&Bs[b_k + 8][b_n] = bv1;
        __syncthreads();
#pragma unroll
        for (int kk = 0; kk < BK; kk++) {
            float4 a0 = *(const float4*)&As[kk][ty * 8];
            float4 a1 = *(const float4*)&As[kk][ty * 8 + 4];
            float4 b0 = *(const float4*)&Bs[kk][tx * 8];
            float4 b1 = *(const float4*)&Bs[kk][tx * 8 + 4];
            float ar[8] = {a0.x, a0.y, a0.z, a0.w, a1.x, a1.y, a1.z, a1.w};
            float br[8] = {b0.x, b0.y, b0.z, b0.w, b1.x, b1.y, b1.z, b1.w};
#pragma unroll
            for (int i = 0; i < 8; i++)
#pragma unroll
                for (int j = 0; j < 8; j++)
                    acc[i][j] = fmaf(ar[i], br[j], acc[i][j]);
        }
    }

    // epilogue: bias + tanh + store (+ norm accumulation)
    const int gc0 = n0 + tx * 8;
    float bv[8];
    {
        float4 t0 = *(const float4*)&bias[gc0];
        float4 t1 = *(const float4*)&bias[gc0 + 4];
        bv[0]=t0.x; bv[1]=t0.y; bv[2]=t0.z; bv[3]=t0.w;
        bv[4]=t1.x; bv[5]=t1.y; bv[6]=t1.z; bv[7]=t1.w;
    }
    float s1 = 0.0f, s2 = 0.0f;
#pragma unroll
    for (int i = 0; i < 8; i++) {
        const int gr = m0 + ty * 8 + i;
        float t[8];
#pragma unroll
        for (int j = 0; j < 8; j++) t[j] = tanhf(acc[i][j] + bv[j]);
        *(float4*)&Out[(size_t)gr * ldo + gc0]     = make_float4(t[0], t[1], t[2], t[3]);
        *(float4*)&Out[(size_t)gr * ldo + gc0 + 4] = make_float4(t[4], t[5], t[6], t[7]);
        if (doNorm) {
            float4 xa = *(const float4*)&A[(size_t)gr * lda + gc0];
            float4 xb = *(const float4*)&A[(size_t)gr * lda + gc0 + 4];
            float xr[8] = {xa.x, xa.y, xa.z, xa.w, xb.x, xb.y, xb.z, xb.w};
#pragma unroll
            for (int j = 0; j < 8; j++) {
                float g = t[j] - xr[j];
                s1 = fmaf(g, g, s1);
                s2 = fmaf(t[j], t[j], s2);
            }
        }
    }
    if (doNorm) {
#pragma unroll
        for (int off = 32; off > 0; off >>= 1) {
            s1 += __shfl_down(s1, off);
            s2 += __shfl_down(s2, off);
        }
        __shared__ float rs[8];
        int lane = tid & 63, wave = tid >> 6;
        if (lane == 0) { rs[wave * 2] = s1; rs[wave * 2 + 1] = s2; }
        __syncthreads();
        if (tid == 0) {
            atomicAdd(&normAcc[0], rs[0] + rs[2] + rs[4] + rs[6]);
            atomicAdd(&normAcc[1], rs[1] + rs[3] + rs[5] + rs[7]);
        }
    }
}

// ---------------------------------------------------------------------------
// per-batch Gram (G = F - X over n slots) + bordered-system LU solve -> alpha
// one block (256 thr) per batch row
// ---------------------------------------------------------------------------
__global__ __launch_bounds__(256) void gram_solve_kernel(
    const float* __restrict__ F, const float* __restrict__ X,
    float* __restrict__ alpha, int n)
{
    const int b = blockIdx.x;
    const int tid = threadIdx.x;
    const float* fb = F + (size_t)b * XROWS;
    const float* xb = X + (size_t)b * XROWS;

    float acc[21];
#pragma unroll
    for (int p = 0; p < 21; p++) acc[p] = 0.0f;

    for (int pos = tid; pos < DIM; pos += 256) {
        float g[6];
#pragma unroll
        for (int i = 0; i < 6; i++)
            g[i] = fb[i * DIM + pos] - xb[i * DIM + pos];  // slots >= n hold garbage; never used
        int p = 0;
#pragma unroll
        for (int i = 0; i < 6; i++)
#pragma unroll 6
            for (int j = i; j < 6; j++) {
                acc[p] = fmaf(g[i], g[j], acc[p]);
                p++;
            }
    }
    // wave reduce 21 partials
#pragma unroll
    for (int p = 0; p < 21; p++) {
        float v = acc[p];
#pragma unroll
        for (int off = 32; off > 0; off >>= 1) v += __shfl_down(v, off);
        acc[p] = v;
    }
    __shared__ float red[4][21];
    __shared__ float Hs[7][8];
    __shared__ float sol[7];
    int lane = tid & 63, wave = tid >> 6;
    if (lane == 0) {
#pragma unroll
        for (int p = 0; p < 21; p++) red[wave][p] = acc[p];
    }
    __syncthreads();

    if (tid == 0) {
        const int np = n + 1;
        // default-init H (identity outside active block), rhs in col 7
        for (int i = 0; i < 7; i++) {
            for (int j = 0; j < 7; j++) Hs[i][j] = (i == j) ? 1.0f : 0.0f;
            Hs[i][7] = (i == 0) ? 1.0f : 0.0f;
        }
        Hs[0][0] = 0.0f;
        for (int j = 1; j <= n; j++) { Hs[0][j] = 1.0f; Hs[j][0] = 1.0f; }
        int p = 0;
        for (int i = 0; i < 6; i++) {
            for (int j = i; j < 6; j++) {
                if (i < n && j < n) {
                    float v = red[0][p] + red[1][p] + red[2][p] + red[3][p];
                    if (i == j) v += LAMREG;
                    Hs[i + 1][j + 1] = v;
                    Hs[j + 1][i + 1] = v;
                }
                p++;
            }
        }
        // Gaussian elimination w/ partial pivoting on np x np (+rhs col 7)
        for (int c = 0; c < np; c++) {
            int piv = c;
            float mx = fabsf(Hs[c][c]);
            for (int r = c + 1; r < np; r++) {
                float a = fabsf(Hs[r][c]);
                if (a > mx) { mx = a; piv = r; }
            }
            if (piv != c) {
                for (int cc = c; cc <= 7; cc++) {
                    float t = Hs[c][cc]; Hs[c][cc] = Hs[piv][cc]; Hs[piv][cc] = t;
                }
            }
            float inv = 1.0f / Hs[c][c];
            for (int r = c + 1; r < np; r++) {
                float f = Hs[r][c] * inv;
                for (int cc = c; cc <= 7; cc++) Hs[r][cc] -= f * Hs[c][cc];
            }
        }
        for (int c = np - 1; c >= 0; c--) {
            float s = Hs[c][7];
            for (int cc = c + 1; cc < np; cc++) s -= Hs[c][cc] * sol[cc];
            sol[c] = s / Hs[c][c];
        }
        for (int i = 0; i < n; i++) alpha[(size_t)b * MS + i] = sol[i + 1];
    }
}

// ---------------------------------------------------------------------------
// xnew[b,:] = sum_i alpha[b,i] * F[b,i,:]   (BETA == 1.0)  -> X[:,up]
// ---------------------------------------------------------------------------
__global__ __launch_bounds__(256) void xnew_kernel(
    const float* __restrict__ F, const float* __restrict__ alpha,
    float* __restrict__ Xout, int n, int up)
{
    int idx = blockIdx.x * 256 + threadIdx.x;
    int b = idx >> 11;
    int j = idx & (DIM - 1);
    const float* al = alpha + (size_t)b * MS;
    const float* fb = F + (size_t)b * XROWS;
    float s = 0.0f;
    for (int i = 0; i < n; i++) s = fmaf(al[i], fb[i * DIM + j], s);
    Xout[(size_t)b * XROWS + (size_t)up * DIM + j] = s;
}

// ---------------------------------------------------------------------------
// result = X[:, 5]  (final up = 29 % 6 = 5)
// ---------------------------------------------------------------------------
__global__ __launch_bounds__(256) void copy_result_kernel(
    const float* __restrict__ Xout, float* __restrict__ result)
{
    for (int i = blockIdx.x * 256 + threadIdx.x; i < BSZ * DIM; i += gridDim.x * 256) {
        int b = i >> 11;
        int j = i & (DIM - 1);
        result[i] = Xout[(size_t)b * XROWS + 5 * DIM + j];
    }
}

// ---------------------------------------------------------------------------
// traces: absd[t] = sqrt(s_gx), rel[t] = absd / (1e-5 + sqrt(s_f))
// ---------------------------------------------------------------------------
__global__ void finalize_kernel(const float* __restrict__ norms,
                                float* __restrict__ rel, float* __restrict__ absd)
{
    int t = threadIdx.x;
    if (t < NIT) {
        float a = sqrtf(norms[2 * t]);
        float fn = sqrtf(norms[2 * t + 1]);
        absd[t] = a;
        rel[t] = a / (1e-5f + fn);
    }
}

extern "C" void kernel_launch(void* const* d_in, const int* in_sizes, int n_in,
                              void* d_out, int out_size, void* d_ws, size_t ws_size,
                              hipStream_t stream) {
    const float* x0   = (const float*)d_in[0];
    const float* W    = (const float*)d_in[1];
    const float* bias = (const float*)d_in[2];

    float* out    = (float*)d_out;
    float* result = out;                                  // 2048*2048
    float* Xout   = out + (size_t)BSZ * DIM;              // 2048*6*2048
    float* rel    = Xout + (size_t)BSZ * MS * DIM;        // 29
    float* absd   = rel + NIT;                            // 29

    float* F     = (float*)d_ws;                          // 2048*6*2048 floats
    float* alpha = F + (size_t)BSZ * MS * DIM;            // 2048*6
    float* norms = alpha + (size_t)BSZ * MS;              // 2*NIT

    dim3 ggrid(DIM / BN, BSZ / BM);

    // X[:,0] = x0 ; zero norm accumulators
    init_kernel<<<2048, 256, 0, stream>>>(x0, Xout, norms);
    // F[:,0] = f(x0)
    gemm_tanh_kernel<<<ggrid, 256, 0, stream>>>(Xout, XROWS, W, bias,
                                                F, XROWS, nullptr, 0);
    for (int k = 1; k <= NIT; k++) {
        int n = (k < MS) ? k : MS;
        int up = k % MS;
        gram_solve_kernel<<<BSZ, 256, 0, stream>>>(F, Xout, alpha, n);
        xnew_kernel<<<BSZ * DIM / 256, 256, 0, stream>>>(F, alpha, Xout, n, up);
        gemm_tanh_kernel<<<ggrid, 256, 0, stream>>>(Xout + (size_t)up * DIM, XROWS, W, bias,
                                                    F + (size_t)up * DIM, XROWS,
                                                    norms + 2 * (k - 1), 1);
    }
    copy_result_kernel<<<2048, 256, 0, stream>>>(Xout, result);
    finalize_kernel<<<1, 64, 0, stream>>>(norms, rel, absd);
}

// Round 2
// 5697.685 us; speedup vs baseline: 1.9271x; 1.9271x over previous
//
#include <hip/hip_runtime.h>
#include <math.h>

#define BSZ 2048
#define DIM 2048
#define MS 6
#define NIT 29          // k = 1..29
#define LAMREG 1e-4f
#define XROWS (MS*DIM)  // 12288: row stride of the (bsz, 6, d) layouts

typedef __bf16 bf16x8 __attribute__((ext_vector_type(8)));
typedef float  f32x4  __attribute__((ext_vector_type(4)));

__device__ __forceinline__ void async16(const void* g, void* l) {
    __builtin_amdgcn_global_load_lds((const __attribute__((address_space(1))) void*)g,
                                     (__attribute__((address_space(3))) void*)l, 16, 0, 0);
}

// ---------------------------------------------------------------------------
// init: X[:,0] = x0, split-bf16 copy of x0, zero norm accumulators
// ---------------------------------------------------------------------------
__global__ __launch_bounds__(256) void init_kernel(const float* __restrict__ x0,
                                                   float* __restrict__ Xout,
                                                   __bf16* __restrict__ Ahi,
                                                   __bf16* __restrict__ Alo,
                                                   float* __restrict__ norms) {
    int idx = blockIdx.x * 256 + threadIdx.x;
    if (idx < 2 * NIT) norms[idx] = 0.0f;
    for (int i = idx; i < BSZ * DIM; i += gridDim.x * 256) {
        int b = i >> 11;
        int j = i & (DIM - 1);
        float v = x0[i];
        Xout[(size_t)b * XROWS + j] = v;
        __bf16 h = (__bf16)v;
        Ahi[i] = h;
        Alo[i] = (__bf16)(v - (float)h);
    }
}

// ---------------------------------------------------------------------------
// W (K x N, f32) -> W^T split into bf16 hi/lo:  WT[n][k] = W[k][n]
// ---------------------------------------------------------------------------
__global__ __launch_bounds__(256) void wt_split_kernel(const float* __restrict__ W,
                                                       __bf16* __restrict__ WThi,
                                                       __bf16* __restrict__ WTlo) {
    __shared__ float tile[32][33];
    const int tx = threadIdx.x & 31;
    const int ty = threadIdx.x >> 5;      // 0..7
    const int n0 = blockIdx.x * 32;
    const int k0 = blockIdx.y * 32;
#pragma unroll
    for (int i = 0; i < 32; i += 8)
        tile[ty + i][tx] = W[(size_t)(k0 + ty + i) * DIM + n0 + tx];
    __syncthreads();
#pragma unroll
    for (int i = 0; i < 32; i += 8) {
        float v = tile[tx][ty + i];
        __bf16 h = (__bf16)v;
        size_t o = (size_t)(n0 + ty + i) * DIM + k0 + tx;
        WThi[o] = h;
        WTlo[o] = (__bf16)(v - (float)h);
    }
}

// ---------------------------------------------------------------------------
// split-bf16 MFMA GEMM + bias + tanh (+ norm accumulation)
// C = A @ W  with A = Ahi+Alo (M x K bf16, ld 2048), W^T = WThi+WTlo (N x K).
// acc = Ahi*Whi + Alo*Whi + Ahi*Wlo  (lo*lo dropped, ~2^-16 relative)
// 128x128 tile, BK=32, 4 waves (2x2 of 64x64), 16x16x32 MFMA.
// ---------------------------------------------------------------------------
__global__ __launch_bounds__(256) void gemm_mfma_kernel(
    const __bf16* __restrict__ Ahi, const __bf16* __restrict__ Alo,
    const __bf16* __restrict__ WThi, const __bf16* __restrict__ WTlo,
    const float* __restrict__ bias,
    const float* __restrict__ Xf32, int ldx,   // fp32 xnew for the norm (may be null)
    float* __restrict__ Out, int ldo,
    float* __restrict__ normAcc, int doNorm)
{
    __shared__ __align__(16) __bf16 Ash[128 * 32];
    __shared__ __align__(16) __bf16 Asl[128 * 32];
    __shared__ __align__(16) __bf16 Bsh[128 * 32];
    __shared__ __align__(16) __bf16 Bsl[128 * 32];
    __shared__ float rs[8];

    const int tid = threadIdx.x;
    const int l = tid & 63;
    const int w = tid >> 6;
    const int m0 = blockIdx.y * 128;
    const int n0 = blockIdx.x * 128;
    const int wm = (w & 1) * 64;
    const int wn = (w >> 1) * 64;
    const int rl = l & 15;          // row/col within 16-tile
    const int kq = (l >> 4) * 8;    // k-quad offset

    // staging: lane l loads 16B at global (row = srow + 64*q, k-seg), HW puts it
    // at ldsbase + l*16 -> row-major [m][32k] layout, matching that order.
    const int srow = w * 16 + (l >> 2);
    const int scol = (l & 3) * 8;
    const size_t aoff = (size_t)(m0 + srow) * DIM + scol;
    const size_t boff = (size_t)(n0 + srow) * DIM + scol;
    __bf16* lA = (__bf16*)Ash + w * 512;   // w*1024 bytes
    __bf16* lAl = (__bf16*)Asl + w * 512;
    __bf16* lB = (__bf16*)Bsh + w * 512;
    __bf16* lBl = (__bf16*)Bsl + w * 512;

    f32x4 acc[4][4];
#pragma unroll
    for (int t = 0; t < 4; t++)
#pragma unroll
        for (int u = 0; u < 4; u++) acc[t][u] = (f32x4){0.f, 0.f, 0.f, 0.f};

    for (int k0 = 0; k0 < DIM; k0 += 32) {
        async16(Ahi + aoff + k0, lA);
        async16(Ahi + aoff + (size_t)64 * DIM + k0, lA + 2048);
        async16(Alo + aoff + k0, lAl);
        async16(Alo + aoff + (size_t)64 * DIM + k0, lAl + 2048);
        async16(WThi + boff + k0, lB);
        async16(WThi + boff + (size_t)64 * DIM + k0, lB + 2048);
        async16(WTlo + boff + k0, lBl);
        async16(WTlo + boff + (size_t)64 * DIM + k0, lBl + 2048);
        __syncthreads();   // compiler inserts vmcnt(0) drain for the LDS writes

        bf16x8 ah[4], al[4];
#pragma unroll
        for (int t = 0; t < 4; t++) {
            const int ro = (wm + t * 16 + rl) * 32 + kq;
            ah[t] = *(const bf16x8*)&Ash[ro];
            al[t] = *(const bf16x8*)&Asl[ro];
        }
#pragma unroll
        for (int u = 0; u < 4; u++) {
            const int co = (wn + u * 16 + rl) * 32 + kq;
            bf16x8 bh = *(const bf16x8*)&Bsh[co];
            bf16x8 bl = *(const bf16x8*)&Bsl[co];
#pragma unroll
            for (int t = 0; t < 4; t++) {
                acc[t][u] = __builtin_amdgcn_mfma_f32_16x16x32_bf16(ah[t], bh, acc[t][u], 0, 0, 0);
                acc[t][u] = __builtin_amdgcn_mfma_f32_16x16x32_bf16(al[t], bh, acc[t][u], 0, 0, 0);
                acc[t][u] = __builtin_amdgcn_mfma_f32_16x16x32_bf16(ah[t], bl, acc[t][u], 0, 0, 0);
            }
        }
        __syncthreads();
    }

    // epilogue: bias + tanh + store (+ ||f-x||^2, ||f||^2)
    float s1 = 0.0f, s2 = 0.0f;
#pragma unroll
    for (int u = 0; u < 4; u++) {
        const int c = n0 + wn + u * 16 + rl;
        const float bv = bias[c];
#pragma unroll
        for (int t = 0; t < 4; t++) {
            const int rb = m0 + wm + t * 16 + (l >> 4) * 4;
            f32x4 a = acc[t][u];
#pragma unroll
            for (int r = 0; r < 4; r++) {
                float v = tanhf(a[r] + bv);
                Out[(size_t)(rb + r) * ldo + c] = v;
                if (doNorm) {
                    float xv = Xf32[(size_t)(rb + r) * ldx + c];
                    float g = v - xv;
                    s1 = fmaf(g, g, s1);
                    s2 = fmaf(v, v, s2);
                }
            }
        }
    }
    if (doNorm) {
#pragma unroll
        for (int off = 32; off > 0; off >>= 1) {
            s1 += __shfl_down(s1, off);
            s2 += __shfl_down(s2, off);
        }
        if (l == 0) { rs[w * 2] = s1; rs[w * 2 + 1] = s2; }
        __syncthreads();
        if (tid == 0) {
            atomicAdd(&normAcc[0], rs[0] + rs[2] + rs[4] + rs[6]);
            atomicAdd(&normAcc[1], rs[1] + rs[3] + rs[5] + rs[7]);
        }
    }
}

// ---------------------------------------------------------------------------
// per-batch Gram (G = F - X over n slots) + bordered-system LU solve -> alpha
// ---------------------------------------------------------------------------
__global__ __launch_bounds__(256) void gram_solve_kernel(
    const float* __restrict__ F, const float* __restrict__ X,
    float* __restrict__ alpha, int n)
{
    const int b = blockIdx.x;
    const int tid = threadIdx.x;
    const float* fb = F + (size_t)b * XROWS;
    const float* xb = X + (size_t)b * XROWS;

    float acc[21];
#pragma unroll
    for (int p = 0; p < 21; p++) acc[p] = 0.0f;

    for (int pos = tid; pos < DIM; pos += 256) {
        float g[6];
#pragma unroll
        for (int i = 0; i < 6; i++)
            g[i] = fb[i * DIM + pos] - xb[i * DIM + pos];
        int p = 0;
#pragma unroll
        for (int i = 0; i < 6; i++)
#pragma unroll 6
            for (int j = i; j < 6; j++) {
                acc[p] = fmaf(g[i], g[j], acc[p]);
                p++;
            }
    }
#pragma unroll
    for (int p = 0; p < 21; p++) {
        float v = acc[p];
#pragma unroll
        for (int off = 32; off > 0; off >>= 1) v += __shfl_down(v, off);
        acc[p] = v;
    }
    __shared__ float red[4][21];
    __shared__ float Hs[7][8];
    __shared__ float sol[7];
    int lane = tid & 63, wave = tid >> 6;
    if (lane == 0) {
#pragma unroll
        for (int p = 0; p < 21; p++) red[wave][p] = acc[p];
    }
    __syncthreads();

    if (tid == 0) {
        const int np = n + 1;
        for (int i = 0; i < 7; i++) {
            for (int j = 0; j < 7; j++) Hs[i][j] = (i == j) ? 1.0f : 0.0f;
            Hs[i][7] = (i == 0) ? 1.0f : 0.0f;
        }
        Hs[0][0] = 0.0f;
        for (int j = 1; j <= n; j++) { Hs[0][j] = 1.0f; Hs[j][0] = 1.0f; }
        int p = 0;
        for (int i = 0; i < 6; i++) {
            for (int j = i; j < 6; j++) {
                if (i < n && j < n) {
                    float v = red[0][p] + red[1][p] + red[2][p] + red[3][p];
                    if (i == j) v += LAMREG;
                    Hs[i + 1][j + 1] = v;
                    Hs[j + 1][i + 1] = v;
                }
                p++;
            }
        }
        for (int c = 0; c < np; c++) {
            int piv = c;
            float mx = fabsf(Hs[c][c]);
            for (int r = c + 1; r < np; r++) {
                float a = fabsf(Hs[r][c]);
                if (a > mx) { mx = a; piv = r; }
            }
            if (piv != c) {
                for (int cc = c; cc <= 7; cc++) {
                    float t = Hs[c][cc]; Hs[c][cc] = Hs[piv][cc]; Hs[piv][cc] = t;
                }
            }
            float inv = 1.0f / Hs[c][c];
            for (int r = c + 1; r < np; r++) {
                float f = Hs[r][c] * inv;
                for (int cc = c; cc <= 7; cc++) Hs[r][cc] -= f * Hs[c][cc];
            }
        }
        for (int c = np - 1; c >= 0; c--) {
            float s = Hs[c][7];
            for (int cc = c + 1; cc < np; cc++) s -= Hs[c][cc] * sol[cc];
            sol[c] = s / Hs[c][c];
        }
        for (int i = 0; i < n; i++) alpha[(size_t)b * MS + i] = sol[i + 1];
    }
}

// ---------------------------------------------------------------------------
// xnew = sum_i alpha_i F[:,i]  -> X[:,up] (f32) and split-bf16 GEMM input
// ---------------------------------------------------------------------------
__global__ __launch_bounds__(256) void xnew_kernel(
    const float* __restrict__ F, const float* __restrict__ alpha,
    float* __restrict__ Xout, __bf16* __restrict__ Ahi, __bf16* __restrict__ Alo,
    int n, int up)
{
    int idx = blockIdx.x * 256 + threadIdx.x;
    int b = idx >> 11;
    int j = idx & (DIM - 1);
    const float* al = alpha + (size_t)b * MS;
    const float* fb = F + (size_t)b * XROWS;
    float s = 0.0f;
    for (int i = 0; i < n; i++) s = fmaf(al[i], fb[i * DIM + j], s);
    Xout[(size_t)b * XROWS + (size_t)up * DIM + j] = s;
    __bf16 h = (__bf16)s;
    Ahi[idx] = h;
    Alo[idx] = (__bf16)(s - (float)h);
}

__global__ __launch_bounds__(256) void copy_result_kernel(
    const float* __restrict__ Xout, float* __restrict__ result)
{
    for (int i = blockIdx.x * 256 + threadIdx.x; i < BSZ * DIM; i += gridDim.x * 256) {
        int b = i >> 11;
        int j = i & (DIM - 1);
        result[i] = Xout[(size_t)b * XROWS + 5 * DIM + j];
    }
}

__global__ void finalize_kernel(const float* __restrict__ norms,
                                float* __restrict__ rel, float* __restrict__ absd)
{
    int t = threadIdx.x;
    if (t < NIT) {
        float a = sqrtf(norms[2 * t]);
        float fn = sqrtf(norms[2 * t + 1]);
        absd[t] = a;
        rel[t] = a / (1e-5f + fn);
    }
}

extern "C" void kernel_launch(void* const* d_in, const int* in_sizes, int n_in,
                              void* d_out, int out_size, void* d_ws, size_t ws_size,
                              hipStream_t stream) {
    const float* x0   = (const float*)d_in[0];
    const float* W    = (const float*)d_in[1];
    const float* bias = (const float*)d_in[2];

    float* out    = (float*)d_out;
    float* result = out;
    float* Xout   = out + (size_t)BSZ * DIM;
    float* rel    = Xout + (size_t)BSZ * MS * DIM;
    float* absd   = rel + NIT;

    char* ws = (char*)d_ws;
    float* F     = (float*)ws;                                   // 100.66 MB
    float* alpha = F + (size_t)BSZ * MS * DIM;                   // 48 KB
    float* norms = alpha + (size_t)BSZ * MS;                     // 232 B
    char* p = (char*)(norms + 64);
    size_t off = ((size_t)(p - ws) + 255) & ~(size_t)255;
    __bf16* Ahi  = (__bf16*)(ws + off);  off += (size_t)BSZ * DIM * 2;
    __bf16* Alo  = (__bf16*)(ws + off);  off += (size_t)BSZ * DIM * 2;
    __bf16* WThi = (__bf16*)(ws + off);  off += (size_t)DIM * DIM * 2;
    __bf16* WTlo = (__bf16*)(ws + off);

    dim3 ggrid(16, 16);

    wt_split_kernel<<<dim3(64, 64), 256, 0, stream>>>(W, WThi, WTlo);
    init_kernel<<<2048, 256, 0, stream>>>(x0, Xout, Ahi, Alo, norms);
    gemm_mfma_kernel<<<ggrid, 256, 0, stream>>>(Ahi, Alo, WThi, WTlo, bias,
                                                nullptr, 0, F, XROWS, nullptr, 0);
    for (int k = 1; k <= NIT; k++) {
        int n = (k < MS) ? k : MS;
        int up = k % MS;
        gram_solve_kernel<<<BSZ, 256, 0, stream>>>(F, Xout, alpha, n);
        xnew_kernel<<<BSZ * DIM / 256, 256, 0, stream>>>(F, alpha, Xout, Ahi, Alo, n, up);
        gemm_mfma_kernel<<<ggrid, 256, 0, stream>>>(Ahi, Alo, WThi, WTlo, bias,
                                                    Xout + (size_t)up * DIM, XROWS,
                                                    F + (size_t)up * DIM, XROWS,
                                                    norms + 2 * (k - 1), 1);
    }
    copy_result_kernel<<<2048, 256, 0, stream>>>(Xout, result);
    finalize_kernel<<<1, 64, 0, stream>>>(norms, rel, absd);
}